// Round 1
// baseline (377.090 us; speedup 1.0000x reference)
//
#include <hip/hip_runtime.h>

#define B 8
#define H 2048
#define D 2
#define HH (H*H)
#define TILE 64
#define NT (H/TILE)   /* 32 */
#define INV2PI 0.15915494309189535f

// v_sin_f32 / v_cos_f32 take revolutions (ISA: D = sin(S0*2pi)); our args are
// well within the +-256 rev HW range (|phase| <= ~2 rev).
__device__ __forceinline__ float fsin(float x) { return __builtin_amdgcn_sinf(x * INV2PI); }
__device__ __forceinline__ float fcos(float x) { return __builtin_amdgcn_cosf(x * INV2PI); }

__global__ void k_init(unsigned int* mm) {
    int t = threadIdx.x;
    if (t < B * 2) mm[t] = (t & 1) ? 0u : 0x7f800000u;  // min=+inf, max=0 (a_lat>0)
}

// Per-batch min/max of A_lat = relu(0.5*(A+A^T)) + 1e-6.
// Upper-triangular tile pairs only -> each A element read exactly once (134 MB).
__global__ __launch_bounds__(256) void k_minmax(const float* __restrict__ A,
                                                unsigned int* __restrict__ mm) {
    int b = blockIdx.y;
    int tp = blockIdx.x;
    int ti = 0;
    while (tp >= NT - ti) { tp -= NT - ti; ti++; }
    int tj = ti + tp;

    __shared__ float l2[TILE][TILE + 1];
    const float* Ab = A + (size_t)b * HH;
    int t = threadIdx.x;
    int c = t & 63, r0 = t >> 6;

    // stage T2 = A[b, tj*64+r, ti*64+c] (coalesced in c)
    #pragma unroll
    for (int k = 0; k < 16; k++) {
        int r = r0 + 4 * k;
        l2[r][c] = Ab[(size_t)(tj * TILE + r) * H + ti * TILE + c];
    }
    __syncthreads();

    float mn = 3.0e38f, mx = 0.f;
    #pragma unroll
    for (int k = 0; k < 16; k++) {
        int il = r0 + 4 * k;            // i-local; jl = c
        float aij = Ab[(size_t)(ti * TILE + il) * H + tj * TILE + c]; // coalesced
        float aji = l2[c][il];          // padded stride 65 -> conflict-free
        float v = fmaxf(0.5f * (aij + aji), 0.f) + 1e-6f;
        mn = fminf(mn, v); mx = fmaxf(mx, v);
    }
    #pragma unroll
    for (int off = 32; off; off >>= 1) {
        mn = fminf(mn, __shfl_xor(mn, off));
        mx = fmaxf(mx, __shfl_xor(mx, off));
    }
    __shared__ float smn[4], smx[4];
    int wv = t >> 6, ln = t & 63;
    if (ln == 0) { smn[wv] = mn; smx[wv] = mx; }
    __syncthreads();
    if (t == 0) {
        for (int i = 1; i < 4; i++) { mn = fminf(mn, smn[i]); mx = fmaxf(mx, smx[i]); }
        atomicMin(&mm[b * 2 + 0], __float_as_uint(mn));
        atomicMax(&mm[b * 2 + 1], __float_as_uint(mx));
    }
}

// Main: grid (NT, B), 1024 threads = 16 waves. Wave w owns i_local in [4w,4w+4),
// lanes span j within a 64-wide j-tile; j-tiles swept sequentially.
__global__ __launch_bounds__(1024) void k_main(
    const float* __restrict__ theta, const float* __restrict__ gamma,
    const float* __restrict__ A, const float* __restrict__ omega,
    const float* __restrict__ kappa, const float* __restrict__ dl,
    const unsigned int* __restrict__ mm, float* __restrict__ out) {
    int b = blockIdx.y;
    int i0 = blockIdx.x * TILE;
    int t = threadIdx.x;
    int w = t >> 6, ln = t & 63;

    __shared__ float aT[TILE][TILE + 1];   // A[b, j0+jl, i0+il]
    __shared__ float dT[TILE][TILE + 1];   // dl[j0+jl, i0+il]
    __shared__ float thI[4][TILE];         // s0,c0,s1,c1 for i-tile
    __shared__ float thJ[4][TILE];         // s0,c0,s1,c1 for j-tile

    float amin = __uint_as_float(mm[b * 2 + 0]);
    float amax = __uint_as_float(mm[b * 2 + 1]);
    float cmin = 1.0f / amax;              // cost monotone decreasing in a_lat
    float cmax = 1.0f / amin;
    float invr = 1.0f / (cmax - cmin + 1e-6f);

    if (t < 128) {
        int il = t & 63, d = t >> 6;
        float th = theta[(size_t)(b * H + i0 + il) * D + d];
        thI[d * 2 + 0][il] = fsin(th);
        thI[d * 2 + 1][il] = fcos(th);
    }
    __syncthreads();

    float si[4][2], ci[4][2];
    #pragma unroll
    for (int k = 0; k < 4; k++) {
        int il = w * 4 + k;
        #pragma unroll
        for (int d = 0; d < 2; d++) {
            si[k][d] = thI[d * 2 + 0][il];
            ci[k][d] = thI[d * 2 + 1][il];
        }
    }

    float acc[4][2] = {};
    const float* Ab = A + (size_t)b * HH;

    for (int jt = 0; jt < NT; jt++) {
        int j0 = jt * TILE;
        __syncthreads();   // previous iteration's readers done before restage
        #pragma unroll
        for (int k = 0; k < 4; k++) {
            int r = w * 4 + k;
            aT[r][ln] = Ab[(size_t)(j0 + r) * H + i0 + ln];   // coalesced
            dT[r][ln] = dl[(size_t)(j0 + r) * H + i0 + ln];
        }
        if (t < 128) {
            int jl = t & 63, d = t >> 6;
            float th = theta[(size_t)(b * H + j0 + jl) * D + d];
            thJ[d * 2 + 0][jl] = fsin(th);
            thJ[d * 2 + 1][jl] = fcos(th);
        }
        __syncthreads();

        float sj0 = thJ[0][ln], cj0 = thJ[1][ln];
        float sj1 = thJ[2][ln], cj1 = thJ[3][ln];
        const float* arow = Ab + (size_t)(i0 + w * 4) * H + j0 + ln;
        const float* drow = dl + (size_t)(i0 + w * 4) * H + j0 + ln;
        #pragma unroll
        for (int k = 0; k < 4; k++) {
            float aij = arow[(size_t)k * H];       // coalesced (L2/LLC-resident)
            float dij = drow[(size_t)k * H];
            float aji = aT[ln][w * 4 + k];         // stride-65 -> conflict-free
            float dji = dT[ln][w * 4 + k];
            float al = fmaxf(0.5f * (aij + aji), 0.f) + 1e-6f;
            float cost = __builtin_amdgcn_rcpf(al);
            float nc = (cost - cmin) * invr;
            float x = dij - dji;                   // |x| <= ~0.08 -> poly tanh exact
            float x2 = x * x;
            float dm = x * fmaf(x2, fmaf(x2, 0.13333334f, -0.33333334f), 1.0f);
            float alpha = dm * nc;
            float sa = fsin(alpha), ca = fcos(alpha);
            {   // d = 0
                float sd = sj0 * ci[k][0] - cj0 * si[k][0];
                float cd = cj0 * ci[k][0] + sj0 * si[k][0];
                acc[k][0] = fmaf(al, sd * ca - cd * sa, acc[k][0]);
            }
            {   // d = 1
                float sd = sj1 * ci[k][1] - cj1 * si[k][1];
                float cd = cj1 * ci[k][1] + sj1 * si[k][1];
                acc[k][1] = fmaf(al, sd * ca - cd * sa, acc[k][1]);
            }
        }
    }

    // butterfly reduce each accumulator over the 64 lanes
    #pragma unroll
    for (int k = 0; k < 4; k++)
        #pragma unroll
        for (int d = 0; d < 2; d++)
            #pragma unroll
            for (int off = 32; off; off >>= 1)
                acc[k][d] += __shfl_xor(acc[k][d], off);

    float chosen = 0.f;
    #pragma unroll
    for (int k = 0; k < 4; k++)
        #pragma unroll
        for (int d = 0; d < 2; d++)
            if (ln == k * 2 + d) chosen = acc[k][d];

    if (ln < 8) {
        int k = ln >> 1, d = ln & 1;
        int i = i0 + w * 4 + k;
        size_t idx = (size_t)(b * H + i) * D + d;
        float th = theta[idx];
        float om = omega[i * D + d];
        float kp = kappa[i * D + d];
        float g  = gamma[b * H + i];
        float drv = kp * fsin(g - th);
        out[idx] = th + (om + (1.0f / H) * chosen + drv);
    }
}

extern "C" void kernel_launch(void* const* d_in, const int* in_sizes, int n_in,
                              void* d_out, int out_size, void* d_ws, size_t ws_size,
                              hipStream_t stream) {
    const float* theta = (const float*)d_in[0];
    const float* gamma = (const float*)d_in[1];
    const float* A     = (const float*)d_in[2];
    const float* omega = (const float*)d_in[3];
    const float* kappa = (const float*)d_in[4];
    const float* dl    = (const float*)d_in[5];
    float* out = (float*)d_out;
    unsigned int* mm = (unsigned int*)d_ws;   // 16 uints: per-batch {min,max} bits

    hipLaunchKernelGGL(k_init,   dim3(1), dim3(64), 0, stream, mm);
    hipLaunchKernelGGL(k_minmax, dim3(NT * (NT + 1) / 2, B), dim3(256), 0, stream, A, mm);
    hipLaunchKernelGGL(k_main,   dim3(NT, B), dim3(1024), 0, stream,
                       theta, gamma, A, omega, kappa, dl, mm, out);
}

// Round 2
// 335.369 us; speedup vs baseline: 1.1244x; 1.1244x over previous
//
#include <hip/hip_runtime.h>
#include <hip/hip_fp16.h>

#define B 8
#define H 2048
#define D 2
#define HH (H*H)
#define TILE 64
#define NT (H/TILE)      /* 32 */
#define NJC 8            /* j-chunks per i-tile */
#define JC (H/NJC)       /* 256 j per block */
#define WJ (JC/4)        /* 64 j per wave */
#define SUB 16           /* j-subtile per LDS stage */
#define NSUB (WJ/SUB)    /* 4 */
#define INV2PI 0.15915494309189535f

// v_sin/v_cos take revolutions; |args| << 256 rev -> safe.
__device__ __forceinline__ float fsin(float x) { return __builtin_amdgcn_sinf(x * INV2PI); }
__device__ __forceinline__ float fcos(float x) { return __builtin_amdgcn_cosf(x * INV2PI); }

// ---------------- primary path ----------------

// Grid (NT, NT): block (ti,tj) writes dm[i,j] = tanh(dl[i,j]-dl[j,i]) as f16 for
// its 64x64 tile (dl read twice total = 32 MB, no mirror pass). First 64 blocks
// also do the elementwise pre-work: sincos table, out base, minmax init.
__global__ __launch_bounds__(256) void k_dmpre(
    const float* __restrict__ dl, __half* __restrict__ dm,
    const float* __restrict__ theta, const float* __restrict__ gamma,
    const float* __restrict__ omega, const float* __restrict__ kappa,
    float* __restrict__ out, float4* __restrict__ sc, unsigned int* __restrict__ mm) {
    int ti = blockIdx.x, tj = blockIdx.y;
    int t = threadIdx.x, c = t & 63, r0 = t >> 6;
    __shared__ float l2[TILE][TILE + 1];

    // stage dl[tj*64+r][ti*64+c] (row-coalesced)
    #pragma unroll
    for (int k = 0; k < 16; k++) {
        int r = r0 + 4 * k;
        l2[r][c] = dl[(size_t)(tj * TILE + r) * H + ti * TILE + c];
    }
    __syncthreads();
    #pragma unroll
    for (int k = 0; k < 16; k++) {
        int il = r0 + 4 * k;
        float x = dl[(size_t)(ti * TILE + il) * H + tj * TILE + c] - l2[c][il];
        float x2 = x * x;  // |x| <= ~0.08 -> 3-term odd poly exact to ~1e-9
        float v = x * fmaf(x2, fmaf(x2, 0.13333334f, -0.33333334f), 1.0f);
        dm[(size_t)(ti * TILE + il) * H + tj * TILE + c] = __float2half(v);
    }

    // elementwise pre-work on first 64 blocks (covers B*H = 16384 (b,i) pairs)
    int bid = blockIdx.y * NT + blockIdx.x;
    if (bid < (B * H) / 256) {
        int g = bid * 256 + t;              // g = b*H + i
        int i = g & (H - 1);
        float th0 = theta[(size_t)g * 2 + 0];
        float th1 = theta[(size_t)g * 2 + 1];
        sc[g] = make_float4(fsin(th0), fcos(th0), fsin(th1), fcos(th1));
        float gm = gamma[g];
        out[(size_t)g * 2 + 0] = th0 + omega[i * 2 + 0] + kappa[i * 2 + 0] * fsin(gm - th0);
        out[(size_t)g * 2 + 1] = th1 + omega[i * 2 + 1] + kappa[i * 2 + 1] * fsin(gm - th1);
        if (g < B * 2) mm[g] = (g & 1) ? 0u : 0x7f800000u;  // min=+inf, max=0
    }
}

// Per-batch min/max of A_lat (unchanged from round 1 — passed, ~HBM-bound).
__global__ __launch_bounds__(256) void k_minmax(const float* __restrict__ A,
                                                unsigned int* __restrict__ mm) {
    int b = blockIdx.y;
    int tp = blockIdx.x;
    int ti = 0;
    while (tp >= NT - ti) { tp -= NT - ti; ti++; }
    int tj = ti + tp;

    __shared__ float l2[TILE][TILE + 1];
    const float* Ab = A + (size_t)b * HH;
    int t = threadIdx.x;
    int c = t & 63, r0 = t >> 6;

    #pragma unroll
    for (int k = 0; k < 16; k++) {
        int r = r0 + 4 * k;
        l2[r][c] = Ab[(size_t)(tj * TILE + r) * H + ti * TILE + c];
    }
    __syncthreads();

    float mn = 3.0e38f, mx = 0.f;
    #pragma unroll
    for (int k = 0; k < 16; k++) {
        int il = r0 + 4 * k;
        float aij = Ab[(size_t)(ti * TILE + il) * H + tj * TILE + c];
        float aji = l2[c][il];
        float v = fmaxf(0.5f * (aij + aji), 0.f) + 1e-6f;
        mn = fminf(mn, v); mx = fmaxf(mx, v);
    }
    #pragma unroll
    for (int off = 32; off; off >>= 1) {
        mn = fminf(mn, __shfl_xor(mn, off));
        mx = fmaxf(mx, __shfl_xor(mx, off));
    }
    __shared__ float smn[4], smx[4];
    int wv = t >> 6, ln = t & 63;
    if (ln == 0) { smn[wv] = mn; smx[wv] = mx; }
    __syncthreads();
    if (t == 0) {
        for (int i = 1; i < 4; i++) { mn = fminf(mn, smn[i]); mx = fmaxf(mx, smx[i]); }
        atomicMin(&mm[b * 2 + 0], __float_as_uint(mn));
        atomicMax(&mm[b * 2 + 1], __float_as_uint(mx));
    }
}

// Main: grid (NT, NJC, B), 256 threads = 4 waves. Lanes = i (64-wide i-tile),
// serial j loop. Wave-private LDS staging of the strided A orientation ->
// NO barriers in the hot loop. Poly sin/cos (|alpha|<=0.08). atomicAdd epilogue.
__global__ __launch_bounds__(256, 8) void k_main(
    const float* __restrict__ A, const __half* __restrict__ dm,
    const float4* __restrict__ sc, const unsigned int* __restrict__ mm,
    float* __restrict__ out) {
    int it = blockIdx.x, jc = blockIdx.y, b = blockIdx.z;
    int t = threadIdx.x, w = t >> 6, ln = t & 63;
    int i0 = it * TILE;
    int i = i0 + ln;

    __shared__ float tile[4][SUB][TILE + 1];  // [wave][j-local][i-local]
    __shared__ float red[4][TILE][2];

    float amin = __uint_as_float(mm[b * 2 + 0]);
    float amax = __uint_as_float(mm[b * 2 + 1]);
    float cmin = 1.0f / amax, cmax = 1.0f / amin;
    float invr = 1.0f / (cmax - cmin + 1e-6f);
    float ncb = cmin * invr;                  // nc = cost*invr - ncb

    const float* Ab = A + (size_t)b * HH;
    const float4* scb = sc + (size_t)b * H;
    float4 sci = scb[i];
    float si0 = sci.x, ci0 = sci.y, si1 = sci.z, ci1 = sci.w;
    float acc0 = 0.f, acc1 = 0.f;

    int jbase = jc * JC + w * WJ;
    int rr = ln >> 2, cc = (ln & 3) * 4;
    for (int st = 0; st < NSUB; st++) {
        int j0 = jbase + st * SUB;
        // stage A[i0..i0+64) x [j0..j0+16) transposed: tile[w][jl][il]
        #pragma unroll
        for (int g = 0; g < 4; g++) {
            int r = rr + g * 16;
            float4 v = *(const float4*)(Ab + (size_t)(i0 + r) * H + j0 + cc);
            tile[w][cc + 0][r] = v.x;
            tile[w][cc + 1][r] = v.y;
            tile[w][cc + 2][r] = v.z;
            tile[w][cc + 3][r] = v.w;
        }
        // same-wave LDS RAW: compiler inserts lgkmcnt wait; no barrier needed
        #pragma unroll 2
        for (int jj = 0; jj < SUB; jj++) {
            int j = j0 + jj;
            float4 scj = scb[j];                         // wave-uniform
            float aji = Ab[(size_t)j * H + i];           // coalesced
            float dmv = __half2float(dm[(size_t)j * H + i]);  // = -dm[i][j]
            float aij = tile[w][jj][ln];                 // conflict-free
            float al = fmaxf(0.5f * (aij + aji), 0.f) + 1e-6f;
            float cost = __builtin_amdgcn_rcpf(al);
            float nc = fmaf(cost, invr, -ncb);
            float alpha = -dmv * nc;                     // dm[i][j]*nc
            float a2 = alpha * alpha;
            float sa = alpha * fmaf(a2, -0.16666667f, 1.0f);
            float ca = fmaf(a2, -0.5f, 1.0f);
            float sd0 = fmaf(scj.x, ci0, -scj.y * si0);  // sin(th_j - th_i)
            float cd0 = fmaf(scj.y, ci0,  scj.x * si0);  // cos(th_j - th_i)
            acc0 = fmaf(al, fmaf(sd0, ca, -cd0 * sa), acc0);
            float sd1 = fmaf(scj.z, ci1, -scj.w * si1);
            float cd1 = fmaf(scj.w, ci1,  scj.z * si1);
            acc1 = fmaf(al, fmaf(sd1, ca, -cd1 * sa), acc1);
        }
    }

    red[w][ln][0] = acc0; red[w][ln][1] = acc1;
    __syncthreads();
    if (w == 0) {
        float r0s = red[0][ln][0] + red[1][ln][0] + red[2][ln][0] + red[3][ln][0];
        float r1s = red[0][ln][1] + red[1][ln][1] + red[2][ln][1] + red[3][ln][1];
        atomicAdd(&out[(size_t)(b * H + i) * 2 + 0], r0s * (1.0f / H));
        atomicAdd(&out[(size_t)(b * H + i) * 2 + 1], r1s * (1.0f / H));
    }
}

// ---------------- fallback path (round-1, known-good; used if ws too small) ----

__global__ void k_init_fb(unsigned int* mm) {
    int t = threadIdx.x;
    if (t < B * 2) mm[t] = (t & 1) ? 0u : 0x7f800000u;
}

__global__ __launch_bounds__(1024) void k_main_fb(
    const float* __restrict__ theta, const float* __restrict__ gamma,
    const float* __restrict__ A, const float* __restrict__ omega,
    const float* __restrict__ kappa, const float* __restrict__ dl,
    const unsigned int* __restrict__ mm, float* __restrict__ out) {
    int b = blockIdx.y;
    int i0 = blockIdx.x * TILE;
    int t = threadIdx.x;
    int w = t >> 6, ln = t & 63;

    __shared__ float aT[TILE][TILE + 1];
    __shared__ float dT[TILE][TILE + 1];
    __shared__ float thI[4][TILE];
    __shared__ float thJ[4][TILE];

    float amin = __uint_as_float(mm[b * 2 + 0]);
    float amax = __uint_as_float(mm[b * 2 + 1]);
    float cmin = 1.0f / amax, cmax = 1.0f / amin;
    float invr = 1.0f / (cmax - cmin + 1e-6f);

    if (t < 128) {
        int il = t & 63, d = t >> 6;
        float th = theta[(size_t)(b * H + i0 + il) * D + d];
        thI[d * 2 + 0][il] = fsin(th);
        thI[d * 2 + 1][il] = fcos(th);
    }
    __syncthreads();

    float si[4][2], ci[4][2];
    #pragma unroll
    for (int k = 0; k < 4; k++)
        #pragma unroll
        for (int d = 0; d < 2; d++) {
            si[k][d] = thI[d * 2 + 0][w * 4 + k];
            ci[k][d] = thI[d * 2 + 1][w * 4 + k];
        }

    float acc[4][2] = {};
    const float* Ab = A + (size_t)b * HH;

    for (int jt = 0; jt < NT; jt++) {
        int j0 = jt * TILE;
        __syncthreads();
        #pragma unroll
        for (int k = 0; k < 4; k++) {
            int r = w * 4 + k;
            aT[r][ln] = Ab[(size_t)(j0 + r) * H + i0 + ln];
            dT[r][ln] = dl[(size_t)(j0 + r) * H + i0 + ln];
        }
        if (t < 128) {
            int jl = t & 63, d = t >> 6;
            float th = theta[(size_t)(b * H + j0 + jl) * D + d];
            thJ[d * 2 + 0][jl] = fsin(th);
            thJ[d * 2 + 1][jl] = fcos(th);
        }
        __syncthreads();

        float sj0 = thJ[0][ln], cj0 = thJ[1][ln];
        float sj1 = thJ[2][ln], cj1 = thJ[3][ln];
        const float* arow = Ab + (size_t)(i0 + w * 4) * H + j0 + ln;
        const float* drow = dl + (size_t)(i0 + w * 4) * H + j0 + ln;
        #pragma unroll
        for (int k = 0; k < 4; k++) {
            float aij = arow[(size_t)k * H];
            float dij = drow[(size_t)k * H];
            float aji = aT[ln][w * 4 + k];
            float dji = dT[ln][w * 4 + k];
            float al = fmaxf(0.5f * (aij + aji), 0.f) + 1e-6f;
            float cost = __builtin_amdgcn_rcpf(al);
            float nc = (cost - cmin) * invr;
            float x = dij - dji;
            float x2 = x * x;
            float dmv = x * fmaf(x2, fmaf(x2, 0.13333334f, -0.33333334f), 1.0f);
            float alpha = dmv * nc;
            float sa = fsin(alpha), ca = fcos(alpha);
            {
                float sd = sj0 * ci[k][0] - cj0 * si[k][0];
                float cd = cj0 * ci[k][0] + sj0 * si[k][0];
                acc[k][0] = fmaf(al, sd * ca - cd * sa, acc[k][0]);
            }
            {
                float sd = sj1 * ci[k][1] - cj1 * si[k][1];
                float cd = cj1 * ci[k][1] + sj1 * si[k][1];
                acc[k][1] = fmaf(al, sd * ca - cd * sa, acc[k][1]);
            }
        }
    }

    #pragma unroll
    for (int k = 0; k < 4; k++)
        #pragma unroll
        for (int d = 0; d < 2; d++)
            #pragma unroll
            for (int off = 32; off; off >>= 1)
                acc[k][d] += __shfl_xor(acc[k][d], off);

    if (ln < 8) {
        int k = ln >> 1, d = ln & 1;
        int i = i0 + w * 4 + k;
        size_t idx = (size_t)(b * H + i) * D + d;
        float chosen = __shfl(acc[k][d], k * 2 + d);
        float th = theta[idx];
        float drv = kappa[i * D + d] * fsin(gamma[b * H + i] - th);
        out[idx] = th + (omega[i * D + d] + (1.0f / H) * chosen + drv);
    }
}

// ---------------- launch ----------------

extern "C" void kernel_launch(void* const* d_in, const int* in_sizes, int n_in,
                              void* d_out, int out_size, void* d_ws, size_t ws_size,
                              hipStream_t stream) {
    const float* theta = (const float*)d_in[0];
    const float* gamma = (const float*)d_in[1];
    const float* A     = (const float*)d_in[2];
    const float* omega = (const float*)d_in[3];
    const float* kappa = (const float*)d_in[4];
    const float* dl    = (const float*)d_in[5];
    float* out = (float*)d_out;

    unsigned int* mm = (unsigned int*)d_ws;                       // 64 B
    float4* sc = (float4*)((char*)d_ws + 1024);                   // 512 KB
    __half* dm = (__half*)((char*)d_ws + 1024 + (size_t)B * H * 16);  // 8 MB
    size_t need = 1024 + (size_t)B * H * 16 + (size_t)HH * 2;

    if (ws_size >= need) {
        hipLaunchKernelGGL(k_dmpre, dim3(NT, NT), dim3(256), 0, stream,
                           dl, dm, theta, gamma, omega, kappa, out, sc, mm);
        hipLaunchKernelGGL(k_minmax, dim3(NT * (NT + 1) / 2, B), dim3(256), 0, stream, A, mm);
        hipLaunchKernelGGL(k_main, dim3(NT, NJC, B), dim3(256), 0, stream,
                           A, dm, sc, mm, out);
    } else {
        hipLaunchKernelGGL(k_init_fb, dim3(1), dim3(64), 0, stream, mm);
        hipLaunchKernelGGL(k_minmax, dim3(NT * (NT + 1) / 2, B), dim3(256), 0, stream, A, mm);
        hipLaunchKernelGGL(k_main_fb, dim3(NT, B), dim3(1024), 0, stream,
                           theta, gamma, A, omega, kappa, dl, mm, out);
    }
}

// Round 3
// 277.207 us; speedup vs baseline: 1.3603x; 1.2098x over previous
//
#include <hip/hip_runtime.h>
#include <hip/hip_fp16.h>

#define B 8
#define H 2048
#define D 2
#define HH (H*H)
#define TILE 64
#define NT (H/TILE)      /* 32 */
#define NPAIR (NT*(NT+1)/2)  /* 528 tile-pairs per batch */
#define NJC 8            /* j-chunks per i-tile */
#define JC (H/NJC)       /* 256 j per block */
#define WJ (JC/4)        /* 64 j per wave */
#define SUB 16           /* j-subtile per LDS stage */
#define NSUB (WJ/SUB)    /* 4 */
#define INV2PI 0.15915494309189535f

// v_sin/v_cos take revolutions; |args| << 256 rev -> safe.
__device__ __forceinline__ float fsin(float x) { return __builtin_amdgcn_sinf(x * INV2PI); }
__device__ __forceinline__ float fcos(float x) { return __builtin_amdgcn_cosf(x * INV2PI); }

// ---------------- primary path ----------------

// Grid (NT, NT): block (ti,tj) writes dm[i,j] = tanh(dl[i,j]-dl[j,i]) as f16.
// First 64 blocks also do elementwise pre-work: sincos table + out base.
__global__ __launch_bounds__(256) void k_dmpre(
    const float* __restrict__ dl, __half* __restrict__ dm,
    const float* __restrict__ theta, const float* __restrict__ gamma,
    const float* __restrict__ omega, const float* __restrict__ kappa,
    float* __restrict__ out, float4* __restrict__ sc) {
    int ti = blockIdx.x, tj = blockIdx.y;
    int t = threadIdx.x, c = t & 63, r0 = t >> 6;
    __shared__ float l2[TILE][TILE + 1];

    float v[16];
    #pragma unroll
    for (int k = 0; k < 16; k++)
        v[k] = dl[(size_t)(tj * TILE + r0 + 4 * k) * H + ti * TILE + c];
    #pragma unroll
    for (int k = 0; k < 16; k++) l2[r0 + 4 * k][c] = v[k];
    __syncthreads();
    #pragma unroll
    for (int k = 0; k < 16; k++)
        v[k] = dl[(size_t)(ti * TILE + r0 + 4 * k) * H + tj * TILE + c];
    #pragma unroll
    for (int k = 0; k < 16; k++) {
        int il = r0 + 4 * k;
        float x = v[k] - l2[c][il];
        float x2 = x * x;  // |x| <= ~0.08 -> 3-term odd poly exact to ~1e-9
        float w = x * fmaf(x2, fmaf(x2, 0.13333334f, -0.33333334f), 1.0f);
        dm[(size_t)(ti * TILE + il) * H + tj * TILE + c] = __float2half(w);
    }

    int bid = blockIdx.y * NT + blockIdx.x;
    if (bid < (B * H) / 256) {
        int g = bid * 256 + t;              // g = b*H + i
        int i = g & (H - 1);
        float th0 = theta[(size_t)g * 2 + 0];
        float th1 = theta[(size_t)g * 2 + 1];
        sc[g] = make_float4(fsin(th0), fcos(th0), fsin(th1), fcos(th1));
        float gm = gamma[g];
        out[(size_t)g * 2 + 0] = th0 + omega[i * 2 + 0] + kappa[i * 2 + 0] * fsin(gm - th0);
        out[(size_t)g * 2 + 1] = th1 + omega[i * 2 + 1] + kappa[i * 2 + 1] * fsin(gm - th1);
    }
}

// Per-batch min/max of A_lat — per-block partials to ws (NO contended atomics;
// 8448 same-line device atomics serialized ~30cyc each = the round-2 110us).
__global__ __launch_bounds__(256) void k_minmax(const float* __restrict__ A,
                                                float* __restrict__ pmn,
                                                float* __restrict__ pmx) {
    int b = blockIdx.y;
    int tp = blockIdx.x;
    int pid = b * NPAIR + tp;
    int ti = 0;
    while (tp >= NT - ti) { tp -= NT - ti; ti++; }
    int tj = ti + tp;

    __shared__ float l2[TILE][TILE + 1];
    const float* Ab = A + (size_t)b * HH;
    int t = threadIdx.x;
    int c = t & 63, r0 = t >> 6;

    float v[16];
    #pragma unroll
    for (int k = 0; k < 16; k++)
        v[k] = Ab[(size_t)(tj * TILE + r0 + 4 * k) * H + ti * TILE + c];
    #pragma unroll
    for (int k = 0; k < 16; k++) l2[r0 + 4 * k][c] = v[k];
    __syncthreads();

    #pragma unroll
    for (int k = 0; k < 16; k++)
        v[k] = Ab[(size_t)(ti * TILE + r0 + 4 * k) * H + tj * TILE + c];

    float mn = 3.0e38f, mx = 0.f;
    #pragma unroll
    for (int k = 0; k < 16; k++) {
        int il = r0 + 4 * k;
        float s = fmaxf(0.5f * (v[k] + l2[c][il]), 0.f) + 1e-6f;
        mn = fminf(mn, s); mx = fmaxf(mx, s);
    }
    #pragma unroll
    for (int off = 32; off; off >>= 1) {
        mn = fminf(mn, __shfl_xor(mn, off));
        mx = fmaxf(mx, __shfl_xor(mx, off));
    }
    __shared__ float smn[4], smx[4];
    int wv = t >> 6, ln = t & 63;
    if (ln == 0) { smn[wv] = mn; smx[wv] = mx; }
    __syncthreads();
    if (t == 0) {
        for (int i = 1; i < 4; i++) { mn = fminf(mn, smn[i]); mx = fmaxf(mx, smx[i]); }
        pmn[pid] = mn;
        pmx[pid] = mx;
    }
}

// One block per batch: reduce 528 partials -> mmf[b*2] = min, mmf[b*2+1] = max.
__global__ __launch_bounds__(256) void k_mmred(const float* __restrict__ pmn,
                                               const float* __restrict__ pmx,
                                               float* __restrict__ mmf) {
    int b = blockIdx.x, t = threadIdx.x;
    float mn = 3.0e38f, mx = 0.f;
    for (int k = t; k < NPAIR; k += 256) {
        mn = fminf(mn, pmn[b * NPAIR + k]);
        mx = fmaxf(mx, pmx[b * NPAIR + k]);
    }
    #pragma unroll
    for (int off = 32; off; off >>= 1) {
        mn = fminf(mn, __shfl_xor(mn, off));
        mx = fmaxf(mx, __shfl_xor(mx, off));
    }
    __shared__ float smn[4], smx[4];
    int wv = t >> 6, ln = t & 63;
    if (ln == 0) { smn[wv] = mn; smx[wv] = mx; }
    __syncthreads();
    if (t == 0) {
        for (int i = 1; i < 4; i++) { mn = fminf(mn, smn[i]); mx = fmaxf(mx, smx[i]); }
        mmf[b * 2 + 0] = mn;
        mmf[b * 2 + 1] = mx;
    }
}

// Main: grid (NT, NJC, B), 256 threads = 4 waves. Lanes = i, serial j loop,
// wave-private LDS staging -> no barriers in hot loop. Poly sin/cos.
__global__ __launch_bounds__(256, 8) void k_main(
    const float* __restrict__ A, const __half* __restrict__ dm,
    const float4* __restrict__ sc, const float* __restrict__ mmf,
    float* __restrict__ out) {
    int it = blockIdx.x, jc = blockIdx.y, b = blockIdx.z;
    int t = threadIdx.x, w = t >> 6, ln = t & 63;
    int i0 = it * TILE;
    int i = i0 + ln;

    __shared__ float tile[4][SUB][TILE + 1];  // [wave][j-local][i-local]
    __shared__ float red[4][TILE][2];

    float amin = mmf[b * 2 + 0];
    float amax = mmf[b * 2 + 1];
    float cmin = 1.0f / amax, cmax = 1.0f / amin;
    float invr = 1.0f / (cmax - cmin + 1e-6f);
    float ncb = cmin * invr;                  // nc = cost*invr - ncb

    const float* Ab = A + (size_t)b * HH;
    const float4* scb = sc + (size_t)b * H;
    float4 sci = scb[i];
    float si0 = sci.x, ci0 = sci.y, si1 = sci.z, ci1 = sci.w;
    float acc0 = 0.f, acc1 = 0.f;

    int jbase = jc * JC + w * WJ;
    int rr = ln >> 2, cc = (ln & 3) * 4;
    for (int st = 0; st < NSUB; st++) {
        int j0 = jbase + st * SUB;
        // stage A[i0..i0+64) x [j0..j0+16) transposed: tile[w][jl][il]
        #pragma unroll
        for (int g = 0; g < 4; g++) {
            int r = rr + g * 16;
            float4 v = *(const float4*)(Ab + (size_t)(i0 + r) * H + j0 + cc);
            tile[w][cc + 0][r] = v.x;
            tile[w][cc + 1][r] = v.y;
            tile[w][cc + 2][r] = v.z;
            tile[w][cc + 3][r] = v.w;
        }
        // same-wave LDS RAW: compiler inserts lgkmcnt wait; no barrier needed
        #pragma unroll 2
        for (int jj = 0; jj < SUB; jj++) {
            int j = j0 + jj;
            float4 scj = scb[j];                         // wave-uniform
            float aji = Ab[(size_t)j * H + i];           // coalesced
            float dmv = __half2float(dm[(size_t)j * H + i]);  // = -dm[i][j]
            float aij = tile[w][jj][ln];                 // conflict-free
            float al = fmaxf(0.5f * (aij + aji), 0.f) + 1e-6f;
            float cost = __builtin_amdgcn_rcpf(al);
            float nc = fmaf(cost, invr, -ncb);
            float alpha = -dmv * nc;                     // dm[i][j]*nc
            float a2 = alpha * alpha;
            float sa = alpha * fmaf(a2, -0.16666667f, 1.0f);
            float ca = fmaf(a2, -0.5f, 1.0f);
            float sd0 = fmaf(scj.x, ci0, -scj.y * si0);  // sin(th_j - th_i)
            float cd0 = fmaf(scj.y, ci0,  scj.x * si0);  // cos(th_j - th_i)
            acc0 = fmaf(al, fmaf(sd0, ca, -cd0 * sa), acc0);
            float sd1 = fmaf(scj.z, ci1, -scj.w * si1);
            float cd1 = fmaf(scj.w, ci1,  scj.z * si1);
            acc1 = fmaf(al, fmaf(sd1, ca, -cd1 * sa), acc1);
        }
    }

    red[w][ln][0] = acc0; red[w][ln][1] = acc1;
    __syncthreads();
    if (w == 0) {
        float r0s = red[0][ln][0] + red[1][ln][0] + red[2][ln][0] + red[3][ln][0];
        float r1s = red[0][ln][1] + red[1][ln][1] + red[2][ln][1] + red[3][ln][1];
        // 8 jc-blocks contend per address, spread over 32K floats -> parallel
        atomicAdd(&out[(size_t)(b * H + i) * 2 + 0], r0s * (1.0f / H));
        atomicAdd(&out[(size_t)(b * H + i) * 2 + 1], r1s * (1.0f / H));
    }
}

// ---------------- fallback path (round-1, known-good; used if ws too small) ----

__global__ void k_init_fb(unsigned int* mm) {
    int t = threadIdx.x;
    if (t < B * 2) mm[t] = (t & 1) ? 0u : 0x7f800000u;
}

__global__ __launch_bounds__(256) void k_minmax_fb(const float* __restrict__ A,
                                                   unsigned int* __restrict__ mm) {
    int b = blockIdx.y;
    int tp = blockIdx.x;
    int ti = 0;
    while (tp >= NT - ti) { tp -= NT - ti; ti++; }
    int tj = ti + tp;

    __shared__ float l2[TILE][TILE + 1];
    const float* Ab = A + (size_t)b * HH;
    int t = threadIdx.x;
    int c = t & 63, r0 = t >> 6;

    #pragma unroll
    for (int k = 0; k < 16; k++)
        l2[r0 + 4 * k][c] = Ab[(size_t)(tj * TILE + r0 + 4 * k) * H + ti * TILE + c];
    __syncthreads();

    float mn = 3.0e38f, mx = 0.f;
    #pragma unroll
    for (int k = 0; k < 16; k++) {
        int il = r0 + 4 * k;
        float aij = Ab[(size_t)(ti * TILE + il) * H + tj * TILE + c];
        float v = fmaxf(0.5f * (aij + l2[c][il]), 0.f) + 1e-6f;
        mn = fminf(mn, v); mx = fmaxf(mx, v);
    }
    #pragma unroll
    for (int off = 32; off; off >>= 1) {
        mn = fminf(mn, __shfl_xor(mn, off));
        mx = fmaxf(mx, __shfl_xor(mx, off));
    }
    __shared__ float smn[4], smx[4];
    int wv = t >> 6, ln = t & 63;
    if (ln == 0) { smn[wv] = mn; smx[wv] = mx; }
    __syncthreads();
    if (t == 0) {
        for (int i = 1; i < 4; i++) { mn = fminf(mn, smn[i]); mx = fmaxf(mx, smx[i]); }
        atomicMin(&mm[b * 2 + 0], __float_as_uint(mn));
        atomicMax(&mm[b * 2 + 1], __float_as_uint(mx));
    }
}

__global__ __launch_bounds__(1024) void k_main_fb(
    const float* __restrict__ theta, const float* __restrict__ gamma,
    const float* __restrict__ A, const float* __restrict__ omega,
    const float* __restrict__ kappa, const float* __restrict__ dl,
    const unsigned int* __restrict__ mm, float* __restrict__ out) {
    int b = blockIdx.y;
    int i0 = blockIdx.x * TILE;
    int t = threadIdx.x;
    int w = t >> 6, ln = t & 63;

    __shared__ float aT[TILE][TILE + 1];
    __shared__ float dT[TILE][TILE + 1];
    __shared__ float thI[4][TILE];
    __shared__ float thJ[4][TILE];

    float amin = __uint_as_float(mm[b * 2 + 0]);
    float amax = __uint_as_float(mm[b * 2 + 1]);
    float cmin = 1.0f / amax, cmax = 1.0f / amin;
    float invr = 1.0f / (cmax - cmin + 1e-6f);

    if (t < 128) {
        int il = t & 63, d = t >> 6;
        float th = theta[(size_t)(b * H + i0 + il) * D + d];
        thI[d * 2 + 0][il] = fsin(th);
        thI[d * 2 + 1][il] = fcos(th);
    }
    __syncthreads();

    float si[4][2], ci[4][2];
    #pragma unroll
    for (int k = 0; k < 4; k++)
        #pragma unroll
        for (int d = 0; d < 2; d++) {
            si[k][d] = thI[d * 2 + 0][w * 4 + k];
            ci[k][d] = thI[d * 2 + 1][w * 4 + k];
        }

    float acc[4][2] = {};
    const float* Ab = A + (size_t)b * HH;

    for (int jt = 0; jt < NT; jt++) {
        int j0 = jt * TILE;
        __syncthreads();
        #pragma unroll
        for (int k = 0; k < 4; k++) {
            int r = w * 4 + k;
            aT[r][ln] = Ab[(size_t)(j0 + r) * H + i0 + ln];
            dT[r][ln] = dl[(size_t)(j0 + r) * H + i0 + ln];
        }
        if (t < 128) {
            int jl = t & 63, d = t >> 6;
            float th = theta[(size_t)(b * H + j0 + jl) * D + d];
            thJ[d * 2 + 0][jl] = fsin(th);
            thJ[d * 2 + 1][jl] = fcos(th);
        }
        __syncthreads();

        float sj0 = thJ[0][ln], cj0 = thJ[1][ln];
        float sj1 = thJ[2][ln], cj1 = thJ[3][ln];
        const float* arow = Ab + (size_t)(i0 + w * 4) * H + j0 + ln;
        const float* drow = dl + (size_t)(i0 + w * 4) * H + j0 + ln;
        #pragma unroll
        for (int k = 0; k < 4; k++) {
            float aij = arow[(size_t)k * H];
            float dij = drow[(size_t)k * H];
            float aji = aT[ln][w * 4 + k];
            float dji = dT[ln][w * 4 + k];
            float al = fmaxf(0.5f * (aij + aji), 0.f) + 1e-6f;
            float cost = __builtin_amdgcn_rcpf(al);
            float nc = (cost - cmin) * invr;
            float x = dij - dji;
            float x2 = x * x;
            float dmv = x * fmaf(x2, fmaf(x2, 0.13333334f, -0.33333334f), 1.0f);
            float alpha = dmv * nc;
            float sa = fsin(alpha), ca = fcos(alpha);
            {
                float sd = sj0 * ci[k][0] - cj0 * si[k][0];
                float cd = cj0 * ci[k][0] + sj0 * si[k][0];
                acc[k][0] = fmaf(al, sd * ca - cd * sa, acc[k][0]);
            }
            {
                float sd = sj1 * ci[k][1] - cj1 * si[k][1];
                float cd = cj1 * ci[k][1] + sj1 * si[k][1];
                acc[k][1] = fmaf(al, sd * ca - cd * sa, acc[k][1]);
            }
        }
    }

    #pragma unroll
    for (int k = 0; k < 4; k++)
        #pragma unroll
        for (int d = 0; d < 2; d++)
            #pragma unroll
            for (int off = 32; off; off >>= 1)
                acc[k][d] += __shfl_xor(acc[k][d], off);

    if (ln < 8) {
        int k = ln >> 1, d = ln & 1;
        int i = i0 + w * 4 + k;
        size_t idx = (size_t)(b * H + i) * D + d;
        float chosen = __shfl(acc[k][d], k * 2 + d);
        float th = theta[idx];
        float drv = kappa[i * D + d] * fsin(gamma[b * H + i] - th);
        out[idx] = th + (omega[i * D + d] + (1.0f / H) * chosen + drv);
    }
}

// ---------------- launch ----------------

extern "C" void kernel_launch(void* const* d_in, const int* in_sizes, int n_in,
                              void* d_out, int out_size, void* d_ws, size_t ws_size,
                              hipStream_t stream) {
    const float* theta = (const float*)d_in[0];
    const float* gamma = (const float*)d_in[1];
    const float* A     = (const float*)d_in[2];
    const float* omega = (const float*)d_in[3];
    const float* kappa = (const float*)d_in[4];
    const float* dl    = (const float*)d_in[5];
    float* out = (float*)d_out;

    // ws layout
    float* mmf = (float*)d_ws;                                    // 64 B
    float* pmn = (float*)((char*)d_ws + 1024);                    // 8*528*4 = 16.9 KB
    float* pmx = pmn + B * NPAIR;
    float4* sc = (float4*)((char*)d_ws + 65536);                  // 256 KB
    __half* dm = (__half*)((char*)d_ws + 65536 + (size_t)B * H * 16);  // 8.4 MB
    size_t need = 65536 + (size_t)B * H * 16 + (size_t)HH * 2;

    if (ws_size >= need) {
        hipLaunchKernelGGL(k_dmpre, dim3(NT, NT), dim3(256), 0, stream,
                           dl, dm, theta, gamma, omega, kappa, out, sc);
        hipLaunchKernelGGL(k_minmax, dim3(NPAIR, B), dim3(256), 0, stream, A, pmn, pmx);
        hipLaunchKernelGGL(k_mmred, dim3(B), dim3(256), 0, stream, pmn, pmx, mmf);
        hipLaunchKernelGGL(k_main, dim3(NT, NJC, B), dim3(256), 0, stream,
                           A, dm, sc, mmf, out);
    } else {
        unsigned int* mm = (unsigned int*)d_ws;
        hipLaunchKernelGGL(k_init_fb, dim3(1), dim3(64), 0, stream, mm);
        hipLaunchKernelGGL(k_minmax_fb, dim3(NPAIR, B), dim3(256), 0, stream, A, mm);
        hipLaunchKernelGGL(k_main_fb, dim3(NT, B), dim3(1024), 0, stream,
                           theta, gamma, A, omega, kappa, dl, mm, out);
    }
}

// Round 4
// 259.186 us; speedup vs baseline: 1.4549x; 1.0695x over previous
//
#include <hip/hip_runtime.h>
#include <hip/hip_fp16.h>
#include <hip/hip_bf16.h>

#define B 8
#define H 2048
#define D 2
#define HH (H*H)
#define TILE 64
#define NT (H/TILE)          /* 32 */
#define NPAIR (NT*(NT+1)/2)  /* 528 upper-tri tile-pairs */
#define INV2PI 0.15915494309189535f
#define INVH (1.0f/2048.0f)

// v_sin/v_cos take revolutions; |args| << 256 rev -> safe.
__device__ __forceinline__ float fsin(float x) { return __builtin_amdgcn_sinf(x * INV2PI); }
__device__ __forceinline__ float fcos(float x) { return __builtin_amdgcn_cosf(x * INV2PI); }

__device__ __forceinline__ void pair_decode(int tp, int& ti, int& tj) {
    ti = 0;
    while (tp >= NT - ti) { tp -= NT - ti; ti++; }
    tj = ti + tp;
}

// ---------------- primary path ----------------
// k_stage: grid (NPAIR, B), 256 thr. Per (b, pair): compute al = relu(.5(A+A^T))+1e-6
// once per unordered pair, store packed bf16; per-block min/max partials.
// b==0 blocks also build packed f16 dm = tanh(dl-dl^T) tiles; b==1/pair<64 do
// the elementwise prework (sincos table + out base).
__global__ __launch_bounds__(256) void k_stage(
    const float* __restrict__ A, const float* __restrict__ dl,
    const float* __restrict__ theta, const float* __restrict__ gamma,
    const float* __restrict__ omega, const float* __restrict__ kappa,
    float* __restrict__ out, float4* __restrict__ sc,
    __hip_bfloat16* __restrict__ alw, __half* __restrict__ dmw,
    float* __restrict__ pmn, float* __restrict__ pmx) {
    int pair = blockIdx.x, b = blockIdx.y;
    int ti, tj; pair_decode(pair, ti, tj);
    int t = threadIdx.x, c = t & 63, r0 = t >> 6;

    __shared__ float l2[TILE][TILE + 1];
    const float* Ab = A + (size_t)b * HH;

    float v[16];
    #pragma unroll
    for (int k = 0; k < 16; k++)
        v[k] = Ab[(size_t)(tj * TILE + r0 + 4 * k) * H + ti * TILE + c];
    #pragma unroll
    for (int k = 0; k < 16; k++) l2[r0 + 4 * k][c] = v[k];
    __syncthreads();
    #pragma unroll
    for (int k = 0; k < 16; k++)
        v[k] = Ab[(size_t)(ti * TILE + r0 + 4 * k) * H + tj * TILE + c];

    __hip_bfloat16* alp = alw + ((size_t)b * NPAIR + pair) * (TILE * TILE);
    float mn = 3.0e38f, mx = 0.f;
    #pragma unroll
    for (int k = 0; k < 16; k++) {
        int il = r0 + 4 * k;
        float al = fmaxf(0.5f * (v[k] + l2[c][il]), 0.f) + 1e-6f;
        mn = fminf(mn, al); mx = fmaxf(mx, al);
        alp[il * TILE + c] = __float2bfloat16(al);   // coalesced ushort stores
    }
    #pragma unroll
    for (int off = 32; off; off >>= 1) {
        mn = fminf(mn, __shfl_xor(mn, off));
        mx = fmaxf(mx, __shfl_xor(mx, off));
    }
    __shared__ float smn[4], smx[4];
    int wv = t >> 6, ln = t & 63;
    if (ln == 0) { smn[wv] = mn; smx[wv] = mx; }
    __syncthreads();
    if (t == 0) {
        for (int i = 1; i < 4; i++) { mn = fminf(mn, smn[i]); mx = fmaxf(mx, smx[i]); }
        pmn[b * NPAIR + pair] = mn;
        pmx[b * NPAIR + pair] = mx;
    }

    if (b == 0) {   // dm tiles (b-independent): reuse LDS after barrier
        __syncthreads();
        float w2[16];
        #pragma unroll
        for (int k = 0; k < 16; k++)
            w2[k] = dl[(size_t)(tj * TILE + r0 + 4 * k) * H + ti * TILE + c];
        #pragma unroll
        for (int k = 0; k < 16; k++) l2[r0 + 4 * k][c] = w2[k];
        __syncthreads();
        #pragma unroll
        for (int k = 0; k < 16; k++)
            w2[k] = dl[(size_t)(ti * TILE + r0 + 4 * k) * H + tj * TILE + c];
        __half* dmp = dmw + (size_t)pair * (TILE * TILE);
        #pragma unroll
        for (int k = 0; k < 16; k++) {
            int il = r0 + 4 * k;
            float x = w2[k] - l2[c][il];
            float x2 = x * x;  // |x| <= ~0.08 -> 3-term odd poly exact to ~1e-9
            float dmv = x * fmaf(x2, fmaf(x2, 0.13333334f, -0.33333334f), 1.0f);
            dmp[il * TILE + c] = __float2half(dmv);
        }
    }

    if (b == 1 && pair < (B * H) / 256) {   // elementwise prework
        int g = pair * 256 + t;             // g = bb*H + i
        int i = g & (H - 1);
        float th0 = theta[(size_t)g * 2 + 0];
        float th1 = theta[(size_t)g * 2 + 1];
        sc[g] = make_float4(fsin(th0), fcos(th0), fsin(th1), fcos(th1));
        float gm = gamma[g];
        out[(size_t)g * 2 + 0] = th0 + omega[i * 2 + 0] + kappa[i * 2 + 0] * fsin(gm - th0);
        out[(size_t)g * 2 + 1] = th1 + omega[i * 2 + 1] + kappa[i * 2 + 1] * fsin(gm - th1);
    }
}

// One block per batch: reduce NPAIR partials -> mmf[b*2]={min}, [b*2+1]={max}.
__global__ __launch_bounds__(256) void k_mmred(const float* __restrict__ pmn,
                                               const float* __restrict__ pmx,
                                               float* __restrict__ mmf) {
    int b = blockIdx.x, t = threadIdx.x;
    float mn = 3.0e38f, mx = 0.f;
    for (int k = t; k < NPAIR; k += 256) {
        mn = fminf(mn, pmn[b * NPAIR + k]);
        mx = fmaxf(mx, pmx[b * NPAIR + k]);
    }
    #pragma unroll
    for (int off = 32; off; off >>= 1) {
        mn = fminf(mn, __shfl_xor(mn, off));
        mx = fmaxf(mx, __shfl_xor(mx, off));
    }
    __shared__ float smn[4], smx[4];
    int wv = t >> 6, ln = t & 63;
    if (ln == 0) { smn[wv] = mn; smx[wv] = mx; }
    __syncthreads();
    if (t == 0) {
        for (int i = 1; i < 4; i++) { mn = fminf(mn, smn[i]); mx = fmaxf(mx, smx[i]); }
        mmf[b * 2 + 0] = mn;
        mmf[b * 2 + 1] = mx;
    }
}

// k_main: grid (NPAIR, B), 256 thr = 4 waves. Upper-tri pairs only; contribution
// of (i,j) to j is the NEGATIVE of its contribution to i (al symmetric, alpha
// antisymmetric), so each unordered pair is computed once and +- scattered.
// Diagonal pairs: row sums only (covers all ordered pairs; i==j term is 0).
__global__ __launch_bounds__(256) void k_main(
    const __hip_bfloat16* __restrict__ alw, const __half* __restrict__ dmw,
    const float4* __restrict__ sc, const float* __restrict__ mmf,
    float* __restrict__ out) {
    int pair = blockIdx.x, b = blockIdx.y;
    int ti, tj; pair_decode(pair, ti, tj);
    bool diag = (ti == tj);
    int t = threadIdx.x, w = t >> 6, ln = t & 63;

    __shared__ float4 ldssc[TILE];     // i-tile sincos
    __shared__ float red[4][TILE][2];  // per-wave col partials

    float amin = mmf[b * 2 + 0];
    float amax = mmf[b * 2 + 1];
    float cmin = 1.0f / amax, cmax = 1.0f / amin;
    float invr = 1.0f / (cmax - cmin + 1e-6f);
    float ncb = cmin * invr;           // nc = cost*invr - ncb

    const float4* scb = sc + (size_t)b * H;
    if (t < TILE) ldssc[t] = scb[ti * TILE + t];

    int j = tj * TILE + ln;
    float4 scj = scb[j];
    float sj0 = scj.x, cj0 = scj.y, sj1 = scj.z, cj1 = scj.w;
    __syncthreads();

    const __hip_bfloat16* alp = alw + ((size_t)b * NPAIR + pair) * (TILE * TILE);
    const __half* dmp = dmw + (size_t)pair * (TILE * TILE);

    float accj0 = 0.f, accj1 = 0.f;    // col (j) accumulators, per lane
    float rs = 0.f;                    // packed row sums: lane 2k+d holds (il=w*16+k, d)

    #pragma unroll
    for (int k = 0; k < 16; k++) {
        int il = w * 16 + k;
        float4 sciv = ldssc[il];       // wave-uniform broadcast
        float si0 = sciv.x, ci0 = sciv.y, si1 = sciv.z, ci1 = sciv.w;

        float al = __bfloat162float(alp[il * TILE + ln]);
        float dmv = __half2float(dmp[il * TILE + ln]);
        float cost = __builtin_amdgcn_rcpf(al);
        float nc = fmaf(cost, invr, -ncb);
        float alpha = dmv * nc;
        float a2 = alpha * alpha;
        float sa = alpha * fmaf(a2, -0.16666667f, 1.0f);
        float ca = fmaf(a2, -0.5f, 1.0f);
        float sd0 = fmaf(sj0, ci0, -cj0 * si0);   // sin(th_j - th_i)
        float cd0 = fmaf(cj0, ci0,  sj0 * si0);   // cos(th_j - th_i)
        float c0 = al * fmaf(sd0, ca, -cd0 * sa); // al*sin(th_j-th_i-alpha)
        float sd1 = fmaf(sj1, ci1, -cj1 * si1);
        float cd1 = fmaf(cj1, ci1,  sj1 * si1);
        float c1 = al * fmaf(sd1, ca, -cd1 * sa);

        accj0 -= c0;                   // scatter to j with negative sign
        accj1 -= c1;

        float s0 = c0, s1 = c1;        // row sum over j-lanes
        #pragma unroll
        for (int off = 32; off; off >>= 1) {
            s0 += __shfl_xor(s0, off);
            s1 += __shfl_xor(s1, off);
        }
        if (ln == 2 * k)     rs = s0;
        if (ln == 2 * k + 1) rs = s1;
    }

    // row (i) atomics: lanes 0..31 hold (k = ln>>1, d = ln&1)
    if (ln < 32) {
        int k = ln >> 1, d = ln & 1;
        int i = ti * TILE + w * 16 + k;
        atomicAdd(&out[(size_t)(b * H + i) * 2 + d], rs * INVH);
    }

    red[w][ln][0] = accj0; red[w][ln][1] = accj1;
    __syncthreads();
    if (!diag && t < 128) {            // col (j) atomics: 2 waves, 128 values
        int jl = t >> 1, d = t & 1;
        float cs = red[0][jl][d] + red[1][jl][d] + red[2][jl][d] + red[3][jl][d];
        atomicAdd(&out[(size_t)(b * H + tj * TILE + jl) * 2 + d], cs * INVH);
    }
}

// ---------------- fallback path (known-good; used if ws too small) ----------

__global__ void k_init_fb(unsigned int* mm) {
    int t = threadIdx.x;
    if (t < B * 2) mm[t] = (t & 1) ? 0u : 0x7f800000u;
}

__global__ __launch_bounds__(256) void k_minmax_fb(const float* __restrict__ A,
                                                   unsigned int* __restrict__ mm) {
    int b = blockIdx.y;
    int tp = blockIdx.x;
    int ti, tj; pair_decode(tp, ti, tj);

    __shared__ float l2[TILE][TILE + 1];
    const float* Ab = A + (size_t)b * HH;
    int t = threadIdx.x;
    int c = t & 63, r0 = t >> 6;

    #pragma unroll
    for (int k = 0; k < 16; k++)
        l2[r0 + 4 * k][c] = Ab[(size_t)(tj * TILE + r0 + 4 * k) * H + ti * TILE + c];
    __syncthreads();

    float mn = 3.0e38f, mx = 0.f;
    #pragma unroll
    for (int k = 0; k < 16; k++) {
        int il = r0 + 4 * k;
        float aij = Ab[(size_t)(ti * TILE + il) * H + tj * TILE + c];
        float v = fmaxf(0.5f * (aij + l2[c][il]), 0.f) + 1e-6f;
        mn = fminf(mn, v); mx = fmaxf(mx, v);
    }
    #pragma unroll
    for (int off = 32; off; off >>= 1) {
        mn = fminf(mn, __shfl_xor(mn, off));
        mx = fmaxf(mx, __shfl_xor(mx, off));
    }
    __shared__ float smn[4], smx[4];
    int wv = t >> 6, ln = t & 63;
    if (ln == 0) { smn[wv] = mn; smx[wv] = mx; }
    __syncthreads();
    if (t == 0) {
        for (int i = 1; i < 4; i++) { mn = fminf(mn, smn[i]); mx = fmaxf(mx, smx[i]); }
        atomicMin(&mm[b * 2 + 0], __float_as_uint(mn));
        atomicMax(&mm[b * 2 + 1], __float_as_uint(mx));
    }
}

__global__ __launch_bounds__(1024) void k_main_fb(
    const float* __restrict__ theta, const float* __restrict__ gamma,
    const float* __restrict__ A, const float* __restrict__ omega,
    const float* __restrict__ kappa, const float* __restrict__ dl,
    const unsigned int* __restrict__ mm, float* __restrict__ out) {
    int b = blockIdx.y;
    int i0 = blockIdx.x * TILE;
    int t = threadIdx.x;
    int w = t >> 6, ln = t & 63;

    __shared__ float aT[TILE][TILE + 1];
    __shared__ float dT[TILE][TILE + 1];
    __shared__ float thI[4][TILE];
    __shared__ float thJ[4][TILE];

    float amin = __uint_as_float(mm[b * 2 + 0]);
    float amax = __uint_as_float(mm[b * 2 + 1]);
    float cmin = 1.0f / amax, cmax = 1.0f / amin;
    float invr = 1.0f / (cmax - cmin + 1e-6f);

    if (t < 128) {
        int il = t & 63, d = t >> 6;
        float th = theta[(size_t)(b * H + i0 + il) * D + d];
        thI[d * 2 + 0][il] = fsin(th);
        thI[d * 2 + 1][il] = fcos(th);
    }
    __syncthreads();

    float si[4][2], ci[4][2];
    #pragma unroll
    for (int k = 0; k < 4; k++)
        #pragma unroll
        for (int d = 0; d < 2; d++) {
            si[k][d] = thI[d * 2 + 0][w * 4 + k];
            ci[k][d] = thI[d * 2 + 1][w * 4 + k];
        }

    float acc[4][2] = {};
    const float* Ab = A + (size_t)b * HH;

    for (int jt = 0; jt < NT; jt++) {
        int j0 = jt * TILE;
        __syncthreads();
        #pragma unroll
        for (int k = 0; k < 4; k++) {
            int r = w * 4 + k;
            aT[r][ln] = Ab[(size_t)(j0 + r) * H + i0 + ln];
            dT[r][ln] = dl[(size_t)(j0 + r) * H + i0 + ln];
        }
        if (t < 128) {
            int jl = t & 63, d = t >> 6;
            float th = theta[(size_t)(b * H + j0 + jl) * D + d];
            thJ[d * 2 + 0][jl] = fsin(th);
            thJ[d * 2 + 1][jl] = fcos(th);
        }
        __syncthreads();

        float sj0 = thJ[0][ln], cj0 = thJ[1][ln];
        float sj1 = thJ[2][ln], cj1 = thJ[3][ln];
        const float* arow = Ab + (size_t)(i0 + w * 4) * H + j0 + ln;
        const float* drow = dl + (size_t)(i0 + w * 4) * H + j0 + ln;
        #pragma unroll
        for (int k = 0; k < 4; k++) {
            float aij = arow[(size_t)k * H];
            float dij = drow[(size_t)k * H];
            float aji = aT[ln][w * 4 + k];
            float dji = dT[ln][w * 4 + k];
            float al = fmaxf(0.5f * (aij + aji), 0.f) + 1e-6f;
            float cost = __builtin_amdgcn_rcpf(al);
            float nc = (cost - cmin) * invr;
            float x = dij - dji;
            float x2 = x * x;
            float dmv = x * fmaf(x2, fmaf(x2, 0.13333334f, -0.33333334f), 1.0f);
            float alpha = dmv * nc;
            float sa = fsin(alpha), ca = fcos(alpha);
            {
                float sd = sj0 * ci[k][0] - cj0 * si[k][0];
                float cd = cj0 * ci[k][0] + sj0 * si[k][0];
                acc[k][0] = fmaf(al, sd * ca - cd * sa, acc[k][0]);
            }
            {
                float sd = sj1 * ci[k][1] - cj1 * si[k][1];
                float cd = cj1 * ci[k][1] + sj1 * si[k][1];
                acc[k][1] = fmaf(al, sd * ca - cd * sa, acc[k][1]);
            }
        }
    }

    #pragma unroll
    for (int k = 0; k < 4; k++)
        #pragma unroll
        for (int d = 0; d < 2; d++)
            #pragma unroll
            for (int off = 32; off; off >>= 1)
                acc[k][d] += __shfl_xor(acc[k][d], off);

    if (ln < 8) {
        int k = ln >> 1, d = ln & 1;
        int i = i0 + w * 4 + k;
        size_t idx = (size_t)(b * H + i) * D + d;
        float chosen = __shfl(acc[k][d], k * 2 + d);
        float th = theta[idx];
        float drv = kappa[i * D + d] * fsin(gamma[b * H + i] - th);
        out[idx] = th + (omega[i * D + d] + (1.0f / H) * chosen + drv);
    }
}

// ---------------- launch ----------------

extern "C" void kernel_launch(void* const* d_in, const int* in_sizes, int n_in,
                              void* d_out, int out_size, void* d_ws, size_t ws_size,
                              hipStream_t stream) {
    const float* theta = (const float*)d_in[0];
    const float* gamma = (const float*)d_in[1];
    const float* A     = (const float*)d_in[2];
    const float* omega = (const float*)d_in[3];
    const float* kappa = (const float*)d_in[4];
    const float* dl    = (const float*)d_in[5];
    float* out = (float*)d_out;

    // ws layout
    float* mmf = (float*)d_ws;                                        // 64 B
    float* pmn = (float*)((char*)d_ws + 1024);                        // 16.9 KB
    float* pmx = pmn + B * NPAIR;
    float4* sc = (float4*)((char*)d_ws + 65536);                      // 256 KB
    __half* dmw = (__half*)((char*)d_ws + 65536 + 262144);            // 4.3 MB
    __hip_bfloat16* alw = (__hip_bfloat16*)((char*)d_ws + 65536 + 262144
                          + (size_t)NPAIR * TILE * TILE * 2);         // 34.6 MB
    size_t need = 65536 + 262144 + (size_t)NPAIR * TILE * TILE * 2
                + (size_t)B * NPAIR * TILE * TILE * 2;

    if (ws_size >= need) {
        hipLaunchKernelGGL(k_stage, dim3(NPAIR, B), dim3(256), 0, stream,
                           A, dl, theta, gamma, omega, kappa, out, sc, alw, dmw, pmn, pmx);
        hipLaunchKernelGGL(k_mmred, dim3(B), dim3(256), 0, stream, pmn, pmx, mmf);
        hipLaunchKernelGGL(k_main, dim3(NPAIR, B), dim3(256), 0, stream,
                           alw, dmw, sc, mmf, out);
    } else {
        unsigned int* mm = (unsigned int*)d_ws;
        hipLaunchKernelGGL(k_init_fb, dim3(1), dim3(64), 0, stream, mm);
        hipLaunchKernelGGL(k_minmax_fb, dim3(NPAIR, B), dim3(256), 0, stream, A, mm);
        hipLaunchKernelGGL(k_main_fb, dim3(NT, B), dim3(1024), 0, stream,
                           theta, gamma, A, omega, kappa, dl, mm, out);
    }
}